// Round 1
// baseline (813.737 us; speedup 1.0000x reference)
//
#include <hip/hip_runtime.h>
#include <hip/hip_bf16.h>
#include <math.h>

// Problem constants
#define BROWS 32768
#define DDIM  4096
#define NEXP  64
#define NCOL  128          // gate (64) + noise (64) fused
#define BM    128          // rows per block
#define BK    64           // k-chunk
#define LDA   72           // padded LDS stride in bf16 elems (64 + 8 -> 16B aligned, banks shift by 4/row)
#define NK    (DDIM / BK)  // 64 chunks

typedef __attribute__((ext_vector_type(8))) short  short8;
typedef __attribute__((ext_vector_type(4))) float  float4v;

static __device__ __forceinline__ unsigned int f2bf_u(float f) {
    union { float f; unsigned int u; } v; v.f = f;
    unsigned int r = v.u + 0x7FFFu + ((v.u >> 16) & 1u);   // RNE
    return r >> 16;
}
static __device__ __forceinline__ unsigned int pk2(float a, float b) {
    return f2bf_u(a) | (f2bf_u(b) << 16);
}

// ---------------------------------------------------------------------------
// Pre-pass: Bt[n][k] = bf16( n<64 ? gate_w[k][n] : w_noise[k][n-64] )
// k-contiguous layout so MFMA B-fragments are ds_read_b128-able.
// ---------------------------------------------------------------------------
__global__ void bt_prepass(const float* __restrict__ gw, const float* __restrict__ wn,
                           unsigned short* __restrict__ Bt) {
    int tid = blockIdx.x * 256 + threadIdx.x;    // 128*4096 total
    int k = tid & (DDIM - 1);
    int n = tid >> 12;
    float v = (n < NEXP) ? gw[(size_t)k * NEXP + n] : wn[(size_t)k * NEXP + (n - NEXP)];
    Bt[(size_t)n * DDIM + k] = (unsigned short)f2bf_u(v);
}

// ---------------------------------------------------------------------------
// Main fused kernel: GEMM (x@[gate_w | w_noise]) + noisy-logits + softmax
// + top-2 + gates + importance/load accumulation.
// ---------------------------------------------------------------------------
__global__ __launch_bounds__(256, 1) void moe_main(
    const float* __restrict__ x, const float* __restrict__ gate_b,
    const float* __restrict__ noise, const unsigned short* __restrict__ Bt,
    float* __restrict__ out_gates, float* __restrict__ out_idx,
    float* __restrict__ g_imp, float* __restrict__ g_load)
{
    // LDS: staging A[2][128][72]b16 (36864B) + B[2][128][72]b16 (36864B) = 73728B
    // epilogue reuses the same region as logits [2][128][66] f32 (67584B)
    __shared__ char smem_raw[73728 + 512];
    unsigned short* As = (unsigned short*)smem_raw;        // [2][128][72]
    unsigned short* Bs = As + 2 * 128 * LDA;               // [2][128][72]
    float* Lq   = (float*)smem_raw;                        // [2][128][66]
    float* impP = (float*)(smem_raw + 73728);              // [64]
    float* ldP  = impP + 64;                               // [64]

    const int tid  = threadIdx.x;
    const int row0 = blockIdx.x * BM;

    // staging mapping: thread -> (row/col sm, k-half sh), 32 elems each
    const int sm = tid >> 1;
    const int sh = tid & 1;
    const float*          xa = x  + (size_t)(row0 + sm) * DDIM + sh * 32;
    const unsigned short* bg = Bt + (size_t)sm * DDIM + sh * 32;

    // compute mapping
    const int wv   = tid >> 6;
    const int ln   = tid & 63;
    const int q    = ln >> 4;
    const int l15  = ln & 15;
    const int wrow = (wv >> 1) * 64;
    const int wcol = (wv & 1) * 64;

    float4 av[8];   // staged A (32 floats)
    uint4  bv[4];   // staged B (32 bf16)
    float4v acc[4][4];
#pragma unroll
    for (int i = 0; i < 4; ++i)
#pragma unroll
        for (int j = 0; j < 4; ++j) acc[i][j] = (float4v)0.f;

    // ---- prologue: stage chunk 0
    {
        const float4* ap = (const float4*)(xa);
        const uint4*  bp = (const uint4*)(bg);
#pragma unroll
        for (int i = 0; i < 8; ++i) av[i] = ap[i];
#pragma unroll
        for (int i = 0; i < 4; ++i) bv[i] = bp[i];
        unsigned short* ad = As + sm * LDA + sh * 32;
        unsigned short* bd = Bs + sm * LDA + sh * 32;
#pragma unroll
        for (int i = 0; i < 4; ++i) {
            uint4 w;
            w.x = pk2(av[2*i].x, av[2*i].y);
            w.y = pk2(av[2*i].z, av[2*i].w);
            w.z = pk2(av[2*i+1].x, av[2*i+1].y);
            w.w = pk2(av[2*i+1].z, av[2*i+1].w);
            ((uint4*)ad)[i] = w;
            ((uint4*)bd)[i] = bv[i];
        }
    }
    __syncthreads();

    for (int c = 0; c < NK; ++c) {
        const int cur = (c & 1) * 128 * LDA;
        // ---- issue next chunk's global loads BEFORE compute (overlap xfer w/ MFMA)
        if (c + 1 < NK) {
            const float4* ap = (const float4*)(xa + (size_t)(c + 1) * BK);
            const uint4*  bp = (const uint4*)(bg + (size_t)(c + 1) * BK);
#pragma unroll
            for (int i = 0; i < 8; ++i) av[i] = ap[i];
#pragma unroll
            for (int i = 0; i < 4; ++i) bv[i] = bp[i];
        }
        // ---- compute chunk c
        {
            const unsigned short* ab = As + cur + (wrow + l15) * LDA + q * 8;
            const unsigned short* bb = Bs + cur + (wcol + l15) * LDA + q * 8;
#pragma unroll
            for (int s = 0; s < 2; ++s) {
                short8 af[4], bfr[4];
#pragma unroll
                for (int mt = 0; mt < 4; ++mt)
                    af[mt] = *(const short8*)(ab + mt * 16 * LDA + s * 32);
#pragma unroll
                for (int nt = 0; nt < 4; ++nt)
                    bfr[nt] = *(const short8*)(bb + nt * 16 * LDA + s * 32);
#pragma unroll
                for (int mt = 0; mt < 4; ++mt)
#pragma unroll
                    for (int nt = 0; nt < 4; ++nt)
                        acc[mt][nt] = __builtin_amdgcn_mfma_f32_16x16x32_bf16(
                            af[mt], bfr[nt], acc[mt][nt], 0, 0, 0);
            }
        }
        // ---- store next chunk to the other LDS buffer
        if (c + 1 < NK) {
            const int nxt = ((c + 1) & 1) * 128 * LDA;
            unsigned short* ad = As + nxt + sm * LDA + sh * 32;
            unsigned short* bd = Bs + nxt + sm * LDA + sh * 32;
#pragma unroll
            for (int i = 0; i < 4; ++i) {
                uint4 w;
                w.x = pk2(av[2*i].x, av[2*i].y);
                w.y = pk2(av[2*i].z, av[2*i].w);
                w.z = pk2(av[2*i+1].x, av[2*i+1].y);
                w.w = pk2(av[2*i+1].z, av[2*i+1].w);
                ((uint4*)ad)[i] = w;
                ((uint4*)bd)[i] = bv[i];
            }
        }
        __syncthreads();
    }

    // ---- epilogue: dump accumulators to LDS logits buffers
    // even waves hold clean (gate) cols, odd waves hold noise cols, per 64-row half
    float* Ldst = Lq + (wv & 1) * (128 * 66);
#pragma unroll
    for (int mt = 0; mt < 4; ++mt)
#pragma unroll
        for (int nt = 0; nt < 4; ++nt)
#pragma unroll
            for (int r = 0; r < 4; ++r) {
                int m = wrow + mt * 16 + q * 4 + r;
                int n = nt * 16 + l15;
                Ldst[m * 66 + n] = acc[mt][nt][r];
            }
    if (tid < 128) ((float*)(smem_raw + 73728))[tid] = 0.f;  // zero impP/ldP
    __syncthreads();

    // ---- per-row: combine, softmax, top-2, outputs. lane = expert.
    const float* Lc = Lq;
    const float* Ln = Lq + 128 * 66;
    const int e = ln;
    const float gb = gate_b[e];
    float imp_acc = 0.f, load_acc = 0.f;

    for (int r32 = 0; r32 < 32; ++r32) {
        const int m = wv * 32 + r32;
        float cl = Lc[m * 66 + e] + gb;
        float nz = Ln[m * 66 + e];
        float nv = noise[(size_t)(row0 + m) * NEXP + e];
        float sp = (nz > 0.f) ? (nz + log1pf(expf(-nz))) : log1pf(expf(nz));
        float lg = cl + nv * sp;

        // top-2 butterfly over 64 lanes, carrying (v1,i1,v2,i2); ties -> lower index
        float v1 = lg, v2 = -INFINITY;
        int   i1 = e,  i2 = 127;
#pragma unroll
        for (int msk = 1; msk < 64; msk <<= 1) {
            float o1 = __shfl_xor(v1, msk, 64);
            int  oi1 = __shfl_xor(i1, msk, 64);
            float o2 = __shfl_xor(v2, msk, 64);
            int  oi2 = __shfl_xor(i2, msk, 64);
            bool ofirst = (o1 > v1) || (o1 == v1 && oi1 < i1);
            if (ofirst) {
                bool t2 = (v1 > o2) || (v1 == o2 && i1 < oi2);
                v2 = t2 ? v1 : o2;  i2 = t2 ? i1 : oi2;
                v1 = o1;            i1 = oi1;
            } else {
                bool t2 = (o1 > v2) || (o1 == v2 && oi1 < i2);
                v2 = t2 ? o1 : v2;  i2 = t2 ? oi1 : i2;
            }
        }
        // softmax probs for importance (v1 is the row max)
        float p = expf(lg - v1);
        float s = p;
#pragma unroll
        for (int msk = 1; msk < 64; msk <<= 1) s += __shfl_xor(s, msk, 64);
        imp_acc += p / s;
        load_acc += (e == i1 ? 1.f : 0.f) + (e == i2 ? 1.f : 0.f);

        if (ln == 0) {
            float g1 = 1.f / (1.f + expf(v2 - v1));
            size_t r = (size_t)(row0 + m) * 2;
            out_gates[r]     = g1;
            out_gates[r + 1] = 1.f - g1;
            out_idx[r]     = (float)i1;
            out_idx[r + 1] = (float)i2;
        }
    }
    atomicAdd(&impP[e], imp_acc);
    atomicAdd(&ldP[e], load_acc);
    __syncthreads();
    if (tid < 64) {
        atomicAdd(&g_imp[tid], impP[tid]);
        atomicAdd(&g_load[tid], ldP[tid]);
    }
}

// ---------------------------------------------------------------------------
// aux_loss = mean(importance * load) * E^2 = 64 * sum(imp*load)
// ---------------------------------------------------------------------------
__global__ void aux_k(const float* __restrict__ imp, const float* __restrict__ ld,
                      float* __restrict__ out) {
    int e = threadIdx.x;
    float s = imp[e] * ld[e];
#pragma unroll
    for (int msk = 1; msk < 64; msk <<= 1) s += __shfl_xor(s, msk, 64);
    if (e == 0) out[0] = s * 64.f;
}

extern "C" void kernel_launch(void* const* d_in, const int* in_sizes, int n_in,
                              void* d_out, int out_size, void* d_ws, size_t ws_size,
                              hipStream_t stream) {
    const float* x     = (const float*)d_in[0];
    const float* gw    = (const float*)d_in[1];
    const float* gb    = (const float*)d_in[2];
    const float* wn    = (const float*)d_in[3];
    const float* noise = (const float*)d_in[4];
    float* out = (float*)d_out;

    float* g_imp  = (float*)d_ws;                               // [64]
    float* g_load = g_imp + 64;                                 // [64]
    unsigned short* Bt = (unsigned short*)((char*)d_ws + 1024); // [128][4096] bf16 = 1MB

    hipMemsetAsync(d_ws, 0, 512, stream);
    bt_prepass<<<dim3((NCOL * DDIM) / 256), dim3(256), 0, stream>>>(gw, wn, Bt);
    moe_main<<<dim3(BROWS / BM), dim3(256), 0, stream>>>(
        x, gb, noise, Bt, out, out + (size_t)BROWS * 2, g_imp, g_load);
    aux_k<<<dim3(1), dim3(64), 0, stream>>>(g_imp, g_load, out + (size_t)BROWS * 4);
}